// Round 1
// baseline (158.414 us; speedup 1.0000x reference)
//
#include <hip/hip_runtime.h>

#define TOPK 8
#define MM 32

__global__ __launch_bounds__(256) void nms_proj_kernel(
    const float* __restrict__ coords, const float* __restrict__ P,
    int* __restrict__ out, int N, int HW)
{
    const float THR2 = 4.0f;
    const float EPSV = 1e-6f;
    const float BIGV = 1e9f;

    int pix = blockIdx.x * blockDim.x + threadIdx.x;
    int total = N * HW;
    if (pix >= total) return;

    int n = pix / HW;           // block-uniform (HW % blockDim == 0)
    int hw = pix - n * HW;

    const float* Pp = P + n * 12;
    float p00 = Pp[0], p01 = Pp[1], p02 = Pp[2],  p03 = Pp[3];
    float p10 = Pp[4], p11 = Pp[5], p12 = Pp[6],  p13 = Pp[7];
    float p20 = Pp[8], p21 = Pp[9], p22 = Pp[10], p23 = Pp[11];

    const float* base = coords + (size_t)n * (MM * 3) * HW + hw;

    // NMS state entirely in registers (static indexing only)
    float kx[TOPK], ky[TOPK];
    int sel[TOPK];
#pragma unroll
    for (int s = 0; s < TOPK; ++s) { kx[s] = BIGV; ky[s] = BIGV; sel[s] = 0; }
    int cnt = 0;

    for (int m = 0; m < MM; ++m) {
        // wave-level early exit: once every lane has 8 kept, nothing can change
        if (__all(cnt >= TOPK)) break;

        const float* cm = base + (size_t)m * (3 * HW);
        float X0 = cm[0];
        float X1 = cm[HW];
        float X2 = cm[2 * HW];

        float xc = p00 * X0 + p01 * X1 + p02 * X2 + p03;
        float yc = p10 * X0 + p11 * X1 + p12 * X2 + p13;
        float zc = p20 * X0 + p21 * X1 + p22 * X2 + p23;
        float z  = fmaxf(zc, EPSV);
        float x  = xc / z;
        float y  = yc / z;

        bool sup = false;
#pragma unroll
        for (int s = 0; s < TOPK; ++s) {
            float dx = kx[s] - x;
            float dy = ky[s] - y;
            sup = sup || (dx * dx + dy * dy <= THR2);
        }
        bool keep = (!sup) && (cnt < TOPK);
        if (keep) {
#pragma unroll
            for (int s = 0; s < TOPK; ++s) {
                if (s == cnt) { kx[s] = x; ky[s] = y; sel[s] = m; }
            }
            cnt++;
        }
    }

    // 32 B per thread, consecutive threads -> coalesced int4 stores
    int4* o = reinterpret_cast<int4*>(out + (size_t)pix * TOPK);
    o[0] = make_int4(sel[0], sel[1], sel[2], sel[3]);
    o[1] = make_int4(sel[4], sel[5], sel[6], sel[7]);
}

extern "C" void kernel_launch(void* const* d_in, const int* in_sizes, int n_in,
                              void* d_out, int out_size, void* d_ws, size_t ws_size,
                              hipStream_t stream) {
    const float* coords = (const float*)d_in[0];   // [N, M, 3, H, W] fp32
    const float* P      = (const float*)d_in[1];   // [N, 3, 4] fp32
    int* out            = (int*)d_out;             // [N, H, W, TOPK] int32

    int N  = in_sizes[1] / 12;                 // 16
    int HW = in_sizes[0] / (N * MM * 3);       // 120*160 = 19200
    int total = N * HW;

    int block = 256;
    int grid = (total + block - 1) / block;    // 1200 blocks
    nms_proj_kernel<<<grid, block, 0, stream>>>(coords, P, out, N, HW);
}